// Round 1
// baseline (1827.521 us; speedup 1.0000x reference)
//
#include <hip/hip_runtime.h>
#include <stdint.h>

typedef unsigned short u16;
typedef unsigned int   u32;

#define NNODES 10000
#define NEDGES 20000
#define ETOT   30000
#define NHEADS 12
#define CDIM   768
#define FDIM   768
#define KDIM   9216
#define NGRAPH 64
#define MPAD   10112   // 79*128
#define NEG_SLOPE 0.2f

typedef __attribute__((ext_vector_type(8))) short short8;
typedef __attribute__((ext_vector_type(4))) float f32x4;

__device__ __forceinline__ u16 f32_bf16(float f) {
  u32 u = __float_as_uint(f);
  u = (u + 0x7FFFu + ((u >> 16) & 1u)) >> 16;
  return (u16)u;
}
__device__ __forceinline__ u32 enc_f32(float f) {
  u32 u = __float_as_uint(f);
  return (u & 0x80000000u) ? ~u : (u | 0x80000000u);
}
__device__ __forceinline__ float dec_f32(u32 u) {
  u32 v = (u & 0x80000000u) ? (u & 0x7FFFFFFFu) : ~u;
  return __uint_as_float(v);
}

// ---------------- CSR build ----------------
__global__ void k_count(const int* __restrict__ dste, int* __restrict__ counts) {
  int e = blockIdx.x * blockDim.x + threadIdx.x;
  if (e >= ETOT) return;
  int dst;
  if (e < NEDGES) dst = dste[e]; else dst = e - NEDGES;
  atomicAdd(&counts[dst], 1);
}

__global__ void k_scan(const int* __restrict__ counts, int* __restrict__ offs) {
  __shared__ int part[256];
  int t = threadIdx.x;
  const int chunk = 40;  // 256*40 >= 10000
  int beg = t * chunk;
  int end = beg + chunk; if (end > NNODES) end = NNODES;
  int s = 0;
  for (int i = beg; i < end && i < NNODES; i++) s += counts[i];
  part[t] = s;
  __syncthreads();
  for (int d = 1; d < 256; d <<= 1) {
    int v = (t >= d) ? part[t - d] : 0;
    __syncthreads();
    part[t] += v;
    __syncthreads();
  }
  int base = (t == 0) ? 0 : part[t - 1];
  for (int i = beg; i < end && i < NNODES; i++) { offs[i] = base; base += counts[i]; }
  if (t == 255) offs[NNODES] = base;
}

__global__ void k_seed(const int* __restrict__ offs, int* __restrict__ cursor) {
  int n = blockIdx.x * blockDim.x + threadIdx.x;
  if (n < NNODES) cursor[n] = offs[n];
}

__global__ void k_scatter(const int* __restrict__ dste, int* __restrict__ cursor,
                          int* __restrict__ elist) {
  int e = blockIdx.x * blockDim.x + threadIdx.x;
  if (e >= ETOT) return;
  int dst;
  if (e < NEDGES) dst = dste[e]; else dst = e - NEDGES;
  int pos = atomicAdd(&cursor[dst], 1);
  elist[pos] = e;
}

// ---------------- U = W_h @ a (per head, src|dst) -> [768,24] ----------------
__global__ void k_U(const float* __restrict__ W, const float* __restrict__ a_src,
                    const float* __restrict__ a_dst, float* __restrict__ U) {
  int k = blockIdx.x;
  int l = threadIdx.x;  // 64
  const float* Wrow = W + (size_t)k * KDIM;
  for (int o = 0; o < 24; o++) {
    int h = (o < 12) ? o : o - 12;
    const float* av = (o < 12) ? (a_src + h * CDIM) : (a_dst + h * CDIM);
    const float* wr = Wrow + h * CDIM;
    float p = 0.f;
    for (int c = l; c < CDIM; c += 64) p += wr[c] * av[c];
#pragma unroll
    for (int d = 32; d > 0; d >>= 1) p += __shfl_down(p, d, 64);
    if (l == 0) U[k * 24 + o] = p;
  }
}

// ---------------- s,d per node: sd[n,0..11]=s, sd[n,12..23]=d ----------------
__global__ void k_sd(const float* __restrict__ xin, const float* __restrict__ U,
                     float* __restrict__ sd) {
  int n = blockIdx.x;
  int t = threadIdx.x, w = t >> 6, l = t & 63;
  const float* xr = xin + (size_t)n * FDIM;
  for (int q = 0; q < 6; q++) {
    int o = w * 6 + q;
    float p = 0.f;
    for (int k = l; k < FDIM; k += 64) p += xr[k] * U[k * 24 + o];
#pragma unroll
    for (int d = 32; d > 0; d >>= 1) p += __shfl_down(p, d, 64);
    if (l == 0) sd[n * 24 + o] = p;
  }
}

// -------- Bt[c, h*768+k] = W[k, h*768+c], bf16 (B^T for the GEMM) --------
__global__ void k_trans(const float* __restrict__ W, u16* __restrict__ Bt) {
  int h = blockIdx.z;
  int kt = blockIdx.x * 32, ct = blockIdx.y * 32;
  int tx = threadIdx.x, ty = threadIdx.y;
  __shared__ float tile[32][33];
#pragma unroll
  for (int r = 0; r < 4; r++)
    tile[ty + 8 * r][tx] = W[(size_t)(kt + ty + 8 * r) * KDIM + h * CDIM + ct + tx];
  __syncthreads();
#pragma unroll
  for (int r = 0; r < 4; r++)
    Bt[(size_t)(ct + ty + 8 * r) * KDIM + h * CDIM + kt + tx] = f32_bf16(tile[tx][ty + 8 * r]);
}

// ---------------- edge logits + segment max ----------------
__global__ void k_edge1(const float* __restrict__ sd, const int* __restrict__ ei,
                        u32* __restrict__ menc, float* __restrict__ ebuf) {
  int tid = blockIdx.x * blockDim.x + threadIdx.x;
  if (tid >= ETOT * NHEADS) return;
  int e = tid / NHEADS, h = tid - e * NHEADS;
  int src, dst;
  if (e < NEDGES) { src = ei[e]; dst = ei[NEDGES + e]; } else { src = e - NEDGES; dst = src; }
  float v = sd[src * 24 + h] + sd[dst * 24 + 12 + h];
  v = (v > 0.f) ? v : NEG_SLOPE * v;
  ebuf[tid] = v;
  atomicMax(&menc[dst * NHEADS + h], enc_f32(v));
}

// ---------------- exp + segment sum ----------------
__global__ void k_edge2(float* __restrict__ ebuf, const int* __restrict__ ei,
                        const u32* __restrict__ menc, float* __restrict__ den) {
  int tid = blockIdx.x * blockDim.x + threadIdx.x;
  if (tid >= ETOT * NHEADS) return;
  int e = tid / NHEADS, h = tid - e * NHEADS;
  int dst;
  if (e < NEDGES) dst = ei[NEDGES + e]; else dst = e - NEDGES;
  float m = dec_f32(menc[dst * NHEADS + h]);
  float ex = expf(ebuf[tid] - m);
  ebuf[tid] = ex;
  atomicAdd(&den[dst * NHEADS + h], ex);
}

// ------- agg[dst, h, k] = sum_e alpha[e,h] * xin[src_e, k]  (bf16 out) -------
__global__ void k_agg(const float* __restrict__ xin, const int* __restrict__ ei,
                      const int* __restrict__ offs, const int* __restrict__ elist,
                      const float* __restrict__ ebuf, const float* __restrict__ den,
                      u16* __restrict__ agg) {
  int n = blockIdx.x;
  int t = threadIdx.x;  // 256
  __shared__ float invd[NHEADS];
  __shared__ float al[NHEADS];
  if (t < NHEADS) invd[t] = 1.f / (den[n * NHEADS + t] + 1e-16f);
  float acc[NHEADS][3];
#pragma unroll
  for (int h = 0; h < NHEADS; h++) { acc[h][0] = 0.f; acc[h][1] = 0.f; acc[h][2] = 0.f; }
  int beg = offs[n], end = offs[n + 1];
  for (int idx = beg; idx < end; idx++) {
    int e = elist[idx];
    int src;
    if (e < NEDGES) src = ei[e]; else src = e - NEDGES;
    __syncthreads();
    if (t < NHEADS) al[t] = ebuf[e * NHEADS + t] * invd[t];
    __syncthreads();
    float x0 = xin[(size_t)src * FDIM + t];
    float x1 = xin[(size_t)src * FDIM + t + 256];
    float x2 = xin[(size_t)src * FDIM + t + 512];
#pragma unroll
    for (int h = 0; h < NHEADS; h++) {
      float a = al[h];
      acc[h][0] += a * x0; acc[h][1] += a * x1; acc[h][2] += a * x2;
    }
  }
  u16* outr = agg + (size_t)n * KDIM;
#pragma unroll
  for (int h = 0; h < NHEADS; h++) {
    outr[h * CDIM + t]       = f32_bf16(acc[h][0]);
    outr[h * CDIM + t + 256] = f32_bf16(acc[h][1]);
    outr[h * CDIM + t + 512] = f32_bf16(acc[h][2]);
  }
}

// ---- C[MPAD,768] = scale * (A[MPAD,9216] @ Bt[768,9216]^T) + bias  (m97 style) ----
__global__ void k_gemm(const u16* __restrict__ A, const u16* __restrict__ B,
                       float* __restrict__ C, const float* __restrict__ bias, float scale) {
  __shared__ __align__(16) u16 As[128 * 32];
  __shared__ __align__(16) u16 Bs[128 * 32];
  int t = threadIdx.x;
  int w = t >> 6, l = t & 63;
  int col0 = blockIdx.x * 128;   // x = col tile (6) -> consecutive blocks share A row tile
  int row0 = blockIdx.y * 128;   // y = row tile (79)
  int wm = (w >> 1) * 64, wn = (w & 1) * 64;
  f32x4 acc[4][4] = {};
  int idx0 = w * 512 + l * 8;      // element index into the 128x32 tile, chunk 0
  int idx1 = idx0 + 2048;          // chunk 1
  const u16* Ag0 = A + (size_t)(row0 + (idx0 >> 5)) * KDIM + (idx0 & 31);
  const u16* Ag1 = A + (size_t)(row0 + (idx1 >> 5)) * KDIM + (idx1 & 31);
  const u16* Bg0 = B + (size_t)(col0 + (idx0 >> 5)) * KDIM + (idx0 & 31);
  const u16* Bg1 = B + (size_t)(col0 + (idx1 >> 5)) * KDIM + (idx1 & 31);
  u16* As0 = As + w * 512;        // wave-uniform LDS bases (lane scatters +l*16B)
  u16* As1 = As + 2048 + w * 512;
  u16* Bs0 = Bs + w * 512;
  u16* Bs1 = Bs + 2048 + w * 512;
  int lr = l & 15, lk = (l >> 4) * 8;

  for (int k0 = 0; k0 < KDIM; k0 += 32) {
    __builtin_amdgcn_global_load_lds((__attribute__((address_space(1))) void*)(Ag0 + k0),
                                     (__attribute__((address_space(3))) void*)As0, 16, 0, 0);
    __builtin_amdgcn_global_load_lds((__attribute__((address_space(1))) void*)(Ag1 + k0),
                                     (__attribute__((address_space(3))) void*)As1, 16, 0, 0);
    __builtin_amdgcn_global_load_lds((__attribute__((address_space(1))) void*)(Bg0 + k0),
                                     (__attribute__((address_space(3))) void*)Bs0, 16, 0, 0);
    __builtin_amdgcn_global_load_lds((__attribute__((address_space(1))) void*)(Bg1 + k0),
                                     (__attribute__((address_space(3))) void*)Bs1, 16, 0, 0);
    __syncthreads();
    short8 af[4], bf[4];
#pragma unroll
    for (int i = 0; i < 4; i++) af[i] = *(const short8*)(As + (wm + i * 16 + lr) * 32 + lk);
#pragma unroll
    for (int j = 0; j < 4; j++) bf[j] = *(const short8*)(Bs + (wn + j * 16 + lr) * 32 + lk);
#pragma unroll
    for (int i = 0; i < 4; i++)
#pragma unroll
      for (int j = 0; j < 4; j++)
        acc[i][j] = __builtin_amdgcn_mfma_f32_16x16x32_bf16(af[i], bf[j], acc[i][j], 0, 0, 0);
    __syncthreads();
  }

  int lg = l >> 4;
#pragma unroll
  for (int i = 0; i < 4; i++)
#pragma unroll
    for (int j = 0; j < 4; j++)
#pragma unroll
      for (int r = 0; r < 4; r++) {
        int row = row0 + wm + i * 16 + lg * 4 + r;
        int col = col0 + wn + j * 16 + lr;
        C[(size_t)row * FDIM + col] = acc[i][j][r] * scale + bias[col];
      }
}

// ---------------- graph mean pool (batch is sorted) ----------------
__global__ void k_pool(const float* __restrict__ h2, const int* __restrict__ batch,
                       float* __restrict__ g) {
  int gi = blockIdx.x;
  int t = threadIdx.x;  // 256
  int lo = 0, hi = NNODES;
  while (lo < hi) { int mid = (lo + hi) >> 1; if (batch[mid] < gi) lo = mid + 1; else hi = mid; }
  int start = lo;
  lo = start; hi = NNODES;
  while (lo < hi) { int mid = (lo + hi) >> 1; if (batch[mid] < gi + 1) lo = mid + 1; else hi = mid; }
  int end = lo;
  int cnt = end - start; if (cnt < 1) cnt = 1;
  float inv = 1.f / (float)cnt;
  for (int c = t; c < FDIM; c += 256) {
    float s = 0.f;
    for (int n = start; n < end; n++) s += h2[(size_t)n * FDIM + c];
    g[gi * FDIM + c] = s * inv;
  }
}

// ---------------- MLP head ----------------
__global__ void k_mlp(const float* __restrict__ g, const float* __restrict__ w1,
                      const float* __restrict__ b1, const float* __restrict__ w2,
                      const float* __restrict__ b2, float* __restrict__ out) {
  int gi = blockIdx.x;
  int t = threadIdx.x;  // 128
  __shared__ float gs[FDIM];
  __shared__ float zs[128];
  for (int i = t; i < FDIM; i += 128) gs[i] = g[gi * FDIM + i];
  __syncthreads();
  float a = b1[t];
  for (int k = 0; k < FDIM; k++) a += gs[k] * w1[k * 128 + t];
  zs[t] = (a > 0.f) ? a : 0.f;
  __syncthreads();
  if (t < 4) {
    float o = b2[t];
    for (int i = 0; i < 128; i++) o += zs[i] * w2[i * 4 + t];
    out[gi * 4 + t] = o;
  }
}

extern "C" void kernel_launch(void* const* d_in, const int* in_sizes, int n_in,
                              void* d_out, int out_size, void* d_ws, size_t ws_size,
                              hipStream_t stream) {
  const float* x    = (const float*)d_in[0];
  const int*   ei   = (const int*)d_in[1];
  const int*   batch= (const int*)d_in[2];
  const float* W1   = (const float*)d_in[3];
  const float* as1  = (const float*)d_in[4];
  const float* ad1  = (const float*)d_in[5];
  const float* b1   = (const float*)d_in[6];
  const float* W2   = (const float*)d_in[7];
  const float* as2  = (const float*)d_in[8];
  const float* ad2  = (const float*)d_in[9];
  const float* b2   = (const float*)d_in[10];
  const float* mw1  = (const float*)d_in[11];
  const float* mb1  = (const float*)d_in[12];
  const float* mw2  = (const float*)d_in[13];
  const float* mb2  = (const float*)d_in[14];
  float* out = (float*)d_out;
  (void)in_sizes; (void)n_in; (void)out_size; (void)ws_size;

  char* wsb = (char*)d_ws;
  size_t off = 0;
  auto alloc = [&](size_t bytes) -> void* {
    void* p = wsb + off;
    off += (bytes + 255) & ~(size_t)255;
    return p;
  };
  u16*  agg    = (u16*)alloc((size_t)MPAD * KDIM * 2);     // 186.4 MB
  u16*  Bt     = (u16*)alloc((size_t)FDIM * KDIM * 2);     // 14.2 MB
  float* h1    = (float*)alloc((size_t)MPAD * FDIM * 4);   // 31.1 MB
  float* h2    = (float*)alloc((size_t)MPAD * FDIM * 4);   // 31.1 MB
  float* sd    = (float*)alloc((size_t)NNODES * 24 * 4);
  float* U     = (float*)alloc((size_t)FDIM * 24 * 4);
  u32*  menc   = (u32*)alloc((size_t)NNODES * NHEADS * 4);
  float* den   = (float*)alloc((size_t)NNODES * NHEADS * 4);
  float* ebuf  = (float*)alloc((size_t)ETOT * NHEADS * 4);
  int*  counts = (int*)alloc((size_t)NNODES * 4);
  int*  offs   = (int*)alloc((size_t)(NNODES + 1) * 4);
  int*  cursor = (int*)alloc((size_t)NNODES * 4);
  int*  elist  = (int*)alloc((size_t)ETOT * 4);
  float* gbuf  = (float*)alloc((size_t)NGRAPH * FDIM * 4);

  // CSR by dst (edges identical for both layers)
  hipMemsetAsync(counts, 0, NNODES * 4, stream);
  k_count<<<(ETOT + 255) / 256, 256, 0, stream>>>(ei + NEDGES, counts);
  k_scan<<<1, 256, 0, stream>>>(counts, offs);
  k_seed<<<(NNODES + 255) / 256, 256, 0, stream>>>(offs, cursor);
  k_scatter<<<(ETOT + 255) / 256, 256, 0, stream>>>(ei + NEDGES, cursor, elist);

  for (int layer = 0; layer < 2; layer++) {
    const float* xin  = layer ? h1  : x;
    const float* W    = layer ? W2  : W1;
    const float* asrc = layer ? as2 : as1;
    const float* adst = layer ? ad2 : ad1;
    const float* bb   = layer ? b2  : b1;
    float* hout       = layer ? h2  : h1;

    k_U<<<FDIM, 64, 0, stream>>>(W, asrc, adst, U);
    k_sd<<<NNODES, 256, 0, stream>>>(xin, U, sd);
    k_trans<<<dim3(24, 24, 12), dim3(32, 8), 0, stream>>>(W, Bt);
    hipMemsetAsync(menc, 0, (size_t)NNODES * NHEADS * 4, stream);
    hipMemsetAsync(den, 0, (size_t)NNODES * NHEADS * 4, stream);
    k_edge1<<<(ETOT * NHEADS + 255) / 256, 256, 0, stream>>>(sd, ei, menc, ebuf);
    k_edge2<<<(ETOT * NHEADS + 255) / 256, 256, 0, stream>>>(ebuf, ei, menc, den);
    k_agg<<<NNODES, 256, 0, stream>>>(xin, ei, offs, elist, ebuf, den, agg);
    k_gemm<<<dim3(FDIM / 128, MPAD / 128), 256, 0, stream>>>(agg, Bt, hout, bb, 1.f / 12.f);
  }

  k_pool<<<NGRAPH, 256, 0, stream>>>(h2, batch, gbuf);
  k_mlp<<<NGRAPH, 128, 0, stream>>>(gbuf, mw1, mb1, mw2, mb2, out);
}

// Round 2
// 1229.618 us; speedup vs baseline: 1.4863x; 1.4863x over previous
//
#include <hip/hip_runtime.h>
#include <stdint.h>

typedef unsigned short u16;
typedef unsigned int   u32;

#define NNODES 10000
#define NEDGES 20000
#define ETOT   30000
#define NHEADS 12
#define CDIM   768
#define FDIM   768
#define KDIM   9216
#define NGRAPH 64
#define MPAD   10112   // 79*128
#define NEG_SLOPE 0.2f

typedef __attribute__((ext_vector_type(8))) short short8;
typedef __attribute__((ext_vector_type(4))) float f32x4;

__device__ __forceinline__ u16 f32_bf16(float f) {
  u32 u = __float_as_uint(f);
  u = (u + 0x7FFFu + ((u >> 16) & 1u)) >> 16;
  return (u16)u;
}
__device__ __forceinline__ u32 enc_f32(float f) {
  u32 u = __float_as_uint(f);
  return (u & 0x80000000u) ? ~u : (u | 0x80000000u);
}
__device__ __forceinline__ float dec_f32(u32 u) {
  u32 v = (u & 0x80000000u) ? (u & 0x7FFFFFFFu) : ~u;
  return __uint_as_float(v);
}

// ---------------- CSR build ----------------
__global__ void k_count(const int* __restrict__ dste, int* __restrict__ counts) {
  int e = blockIdx.x * blockDim.x + threadIdx.x;
  if (e >= ETOT) return;
  int dst;
  if (e < NEDGES) dst = dste[e]; else dst = e - NEDGES;
  atomicAdd(&counts[dst], 1);
}

__global__ void k_scan(const int* __restrict__ counts, int* __restrict__ offs) {
  __shared__ int part[256];
  int t = threadIdx.x;
  const int chunk = 40;  // 256*40 >= 10000
  int beg = t * chunk;
  int end = beg + chunk; if (end > NNODES) end = NNODES;
  int s = 0;
  for (int i = beg; i < end && i < NNODES; i++) s += counts[i];
  part[t] = s;
  __syncthreads();
  for (int d = 1; d < 256; d <<= 1) {
    int v = (t >= d) ? part[t - d] : 0;
    __syncthreads();
    part[t] += v;
    __syncthreads();
  }
  int base = (t == 0) ? 0 : part[t - 1];
  for (int i = beg; i < end && i < NNODES; i++) { offs[i] = base; base += counts[i]; }
  if (t == 255) offs[NNODES] = base;
}

__global__ void k_seed(const int* __restrict__ offs, int* __restrict__ cursor) {
  int n = blockIdx.x * blockDim.x + threadIdx.x;
  if (n < NNODES) cursor[n] = offs[n];
}

__global__ void k_scatter(const int* __restrict__ dste, int* __restrict__ cursor,
                          int* __restrict__ elist) {
  int e = blockIdx.x * blockDim.x + threadIdx.x;
  if (e >= ETOT) return;
  int dst;
  if (e < NEDGES) dst = dste[e]; else dst = e - NEDGES;
  int pos = atomicAdd(&cursor[dst], 1);
  elist[pos] = e;
}

// ------- Ut[o*768+k] = sum_c W[k, h*768+c] * a[h, c]   (o: 0..11 src, 12..23 dst) -------
__global__ void k_U(const float* __restrict__ W, const float* __restrict__ a_src,
                    const float* __restrict__ a_dst, float* __restrict__ Ut) {
  int k = blockIdx.x;
  int l = threadIdx.x;  // 64
  const float* Wrow = W + (size_t)k * KDIM;
  for (int o = 0; o < 24; o++) {
    int h = (o < 12) ? o : o - 12;
    const float* av = (o < 12) ? (a_src + h * CDIM) : (a_dst + h * CDIM);
    const float* wr = Wrow + h * CDIM;
    float p = 0.f;
    for (int c = l; c < CDIM; c += 64) p += wr[c] * av[c];
#pragma unroll
    for (int d = 32; d > 0; d >>= 1) p += __shfl_down(p, d, 64);
    if (l == 0) Ut[o * FDIM + k] = p;
  }
}

// ---- sd[n,0..11]=s, sd[n,12..23]=d : one wave per node, coalesced float4 loads ----
__global__ void k_sd(const float* __restrict__ xin, const float* __restrict__ Ut,
                     float* __restrict__ sd) {
  int t = threadIdx.x, w = t >> 6, l = t & 63;
  int n = blockIdx.x * 4 + w;
  if (n >= NNODES) return;
  const float* xr = xin + (size_t)n * FDIM;
  float4 x0 = *(const float4*)(xr + 4 * l);
  float4 x1 = *(const float4*)(xr + 4 * l + 256);
  float4 x2 = *(const float4*)(xr + 4 * l + 512);
#pragma unroll
  for (int o = 0; o < 24; o++) {
    const float4* up = (const float4*)(Ut + o * FDIM + 4 * l);
    float4 u0 = up[0];
    float4 u1 = up[64];
    float4 u2 = up[128];
    float a = x0.x * u0.x + x0.y * u0.y + x0.z * u0.z + x0.w * u0.w
            + x1.x * u1.x + x1.y * u1.y + x1.z * u1.z + x1.w * u1.w
            + x2.x * u2.x + x2.y * u2.y + x2.z * u2.z + x2.w * u2.w;
#pragma unroll
    for (int d = 32; d > 0; d >>= 1) a += __shfl_xor(a, d, 64);
    if (l == 0) sd[n * 24 + o] = a;
  }
}

// -------- Bt[c, h*768+k] = W[k, h*768+c], bf16 (B^T for the GEMM) --------
__global__ void k_trans(const float* __restrict__ W, u16* __restrict__ Bt) {
  int h = blockIdx.z;
  int kt = blockIdx.x * 32, ct = blockIdx.y * 32;
  int tx = threadIdx.x, ty = threadIdx.y;
  __shared__ float tile[32][33];
#pragma unroll
  for (int r = 0; r < 4; r++)
    tile[ty + 8 * r][tx] = W[(size_t)(kt + ty + 8 * r) * KDIM + h * CDIM + ct + tx];
  __syncthreads();
#pragma unroll
  for (int r = 0; r < 4; r++)
    Bt[(size_t)(ct + ty + 8 * r) * KDIM + h * CDIM + kt + tx] = f32_bf16(tile[tx][ty + 8 * r]);
}

// ---------------- edge logits + segment max ----------------
__global__ void k_edge1(const float* __restrict__ sd, const int* __restrict__ ei,
                        u32* __restrict__ menc, float* __restrict__ ebuf) {
  int tid = blockIdx.x * blockDim.x + threadIdx.x;
  if (tid >= ETOT * NHEADS) return;
  int e = tid / NHEADS, h = tid - e * NHEADS;
  int src, dst;
  if (e < NEDGES) { src = ei[e]; dst = ei[NEDGES + e]; } else { src = e - NEDGES; dst = src; }
  float v = sd[src * 24 + h] + sd[dst * 24 + 12 + h];
  v = (v > 0.f) ? v : NEG_SLOPE * v;
  ebuf[tid] = v;
  atomicMax(&menc[dst * NHEADS + h], enc_f32(v));
}

// ---------------- exp + segment sum ----------------
__global__ void k_edge2(float* __restrict__ ebuf, const int* __restrict__ ei,
                        const u32* __restrict__ menc, float* __restrict__ den) {
  int tid = blockIdx.x * blockDim.x + threadIdx.x;
  if (tid >= ETOT * NHEADS) return;
  int e = tid / NHEADS, h = tid - e * NHEADS;
  int dst;
  if (e < NEDGES) dst = ei[NEDGES + e]; else dst = e - NEDGES;
  float m = dec_f32(menc[dst * NHEADS + h]);
  float ex = expf(ebuf[tid] - m);
  ebuf[tid] = ex;
  atomicAdd(&den[dst * NHEADS + h], ex);
}

// ------- agg[dst, h, k] = sum_e alpha[e,h] * xin[src_e, k]  (bf16 out) -------
__global__ void k_agg(const float* __restrict__ xin, const int* __restrict__ ei,
                      const int* __restrict__ offs, const int* __restrict__ elist,
                      const float* __restrict__ ebuf, const float* __restrict__ den,
                      u16* __restrict__ agg) {
  int n = blockIdx.x;
  int t = threadIdx.x;  // 256
  __shared__ float invd[NHEADS];
  __shared__ float al[NHEADS];
  if (t < NHEADS) invd[t] = 1.f / (den[n * NHEADS + t] + 1e-16f);
  float acc[NHEADS][3];
#pragma unroll
  for (int h = 0; h < NHEADS; h++) { acc[h][0] = 0.f; acc[h][1] = 0.f; acc[h][2] = 0.f; }
  int beg = offs[n], end = offs[n + 1];
  for (int idx = beg; idx < end; idx++) {
    int e = elist[idx];
    int src;
    if (e < NEDGES) src = ei[e]; else src = e - NEDGES;
    __syncthreads();
    if (t < NHEADS) al[t] = ebuf[e * NHEADS + t] * invd[t];
    __syncthreads();
    float x0 = xin[(size_t)src * FDIM + t];
    float x1 = xin[(size_t)src * FDIM + t + 256];
    float x2 = xin[(size_t)src * FDIM + t + 512];
#pragma unroll
    for (int h = 0; h < NHEADS; h++) {
      float a = al[h];
      acc[h][0] += a * x0; acc[h][1] += a * x1; acc[h][2] += a * x2;
    }
  }
  u16* outr = agg + (size_t)n * KDIM;
#pragma unroll
  for (int h = 0; h < NHEADS; h++) {
    outr[h * CDIM + t]       = f32_bf16(acc[h][0]);
    outr[h * CDIM + t + 256] = f32_bf16(acc[h][1]);
    outr[h * CDIM + t + 512] = f32_bf16(acc[h][2]);
  }
}

// ---- C[MPAD,768] = scale * (A[MPAD,9216] @ Bt[768,9216]^T) + bias  (m97 style) ----
__global__ void k_gemm(const u16* __restrict__ A, const u16* __restrict__ B,
                       float* __restrict__ C, const float* __restrict__ bias, float scale) {
  __shared__ __align__(16) u16 As[128 * 32];
  __shared__ __align__(16) u16 Bs[128 * 32];
  int t = threadIdx.x;
  int w = t >> 6, l = t & 63;
  int col0 = blockIdx.x * 128;   // x = col tile (6) -> consecutive blocks share A row tile
  int row0 = blockIdx.y * 128;   // y = row tile (79)
  int wm = (w >> 1) * 64, wn = (w & 1) * 64;
  f32x4 acc[4][4] = {};
  int idx0 = w * 512 + l * 8;      // element index into the 128x32 tile, chunk 0
  int idx1 = idx0 + 2048;          // chunk 1
  const u16* Ag0 = A + (size_t)(row0 + (idx0 >> 5)) * KDIM + (idx0 & 31);
  const u16* Ag1 = A + (size_t)(row0 + (idx1 >> 5)) * KDIM + (idx1 & 31);
  const u16* Bg0 = B + (size_t)(col0 + (idx0 >> 5)) * KDIM + (idx0 & 31);
  const u16* Bg1 = B + (size_t)(col0 + (idx1 >> 5)) * KDIM + (idx1 & 31);
  u16* As0 = As + w * 512;        // wave-uniform LDS bases (lane scatters +l*16B)
  u16* As1 = As + 2048 + w * 512;
  u16* Bs0 = Bs + w * 512;
  u16* Bs1 = Bs + 2048 + w * 512;
  int lr = l & 15, lk = (l >> 4) * 8;

  for (int k0 = 0; k0 < KDIM; k0 += 32) {
    __builtin_amdgcn_global_load_lds((__attribute__((address_space(1))) void*)(Ag0 + k0),
                                     (__attribute__((address_space(3))) void*)As0, 16, 0, 0);
    __builtin_amdgcn_global_load_lds((__attribute__((address_space(1))) void*)(Ag1 + k0),
                                     (__attribute__((address_space(3))) void*)As1, 16, 0, 0);
    __builtin_amdgcn_global_load_lds((__attribute__((address_space(1))) void*)(Bg0 + k0),
                                     (__attribute__((address_space(3))) void*)Bs0, 16, 0, 0);
    __builtin_amdgcn_global_load_lds((__attribute__((address_space(1))) void*)(Bg1 + k0),
                                     (__attribute__((address_space(3))) void*)Bs1, 16, 0, 0);
    __syncthreads();
    short8 af[4], bf[4];
#pragma unroll
    for (int i = 0; i < 4; i++) af[i] = *(const short8*)(As + (wm + i * 16 + lr) * 32 + lk);
#pragma unroll
    for (int j = 0; j < 4; j++) bf[j] = *(const short8*)(Bs + (wn + j * 16 + lr) * 32 + lk);
#pragma unroll
    for (int i = 0; i < 4; i++)
#pragma unroll
      for (int j = 0; j < 4; j++)
        acc[i][j] = __builtin_amdgcn_mfma_f32_16x16x32_bf16(af[i], bf[j], acc[i][j], 0, 0, 0);
    __syncthreads();
  }

  int lg = l >> 4;
#pragma unroll
  for (int i = 0; i < 4; i++)
#pragma unroll
    for (int j = 0; j < 4; j++)
#pragma unroll
      for (int r = 0; r < 4; r++) {
        int row = row0 + wm + i * 16 + lg * 4 + r;
        int col = col0 + wn + j * 16 + lr;
        C[(size_t)row * FDIM + col] = acc[i][j][r] * scale + bias[col];
      }
}

// ---------------- graph mean pool (batch is sorted) ----------------
__global__ void k_pool(const float* __restrict__ h2, const int* __restrict__ batch,
                       float* __restrict__ g) {
  int gi = blockIdx.x;
  int t = threadIdx.x;  // 256
  int lo = 0, hi = NNODES;
  while (lo < hi) { int mid = (lo + hi) >> 1; if (batch[mid] < gi) lo = mid + 1; else hi = mid; }
  int start = lo;
  lo = start; hi = NNODES;
  while (lo < hi) { int mid = (lo + hi) >> 1; if (batch[mid] < gi + 1) lo = mid + 1; else hi = mid; }
  int end = lo;
  int cnt = end - start; if (cnt < 1) cnt = 1;
  float inv = 1.f / (float)cnt;
  for (int c = t; c < FDIM; c += 256) {
    float s = 0.f;
    for (int n = start; n < end; n++) s += h2[(size_t)n * FDIM + c];
    g[gi * FDIM + c] = s * inv;
  }
}

// ---------------- MLP head ----------------
__global__ void k_mlp(const float* __restrict__ g, const float* __restrict__ w1,
                      const float* __restrict__ b1, const float* __restrict__ w2,
                      const float* __restrict__ b2, float* __restrict__ out) {
  int gi = blockIdx.x;
  int t = threadIdx.x;  // 128
  __shared__ float gs[FDIM];
  __shared__ float zs[128];
  for (int i = t; i < FDIM; i += 128) gs[i] = g[gi * FDIM + i];
  __syncthreads();
  float a = b1[t];
  for (int k = 0; k < FDIM; k++) a += gs[k] * w1[k * 128 + t];
  zs[t] = (a > 0.f) ? a : 0.f;
  __syncthreads();
  if (t < 4) {
    float o = b2[t];
    for (int i = 0; i < 128; i++) o += zs[i] * w2[i * 4 + t];
    out[gi * 4 + t] = o;
  }
}

extern "C" void kernel_launch(void* const* d_in, const int* in_sizes, int n_in,
                              void* d_out, int out_size, void* d_ws, size_t ws_size,
                              hipStream_t stream) {
  const float* x    = (const float*)d_in[0];
  const int*   ei   = (const int*)d_in[1];
  const int*   batch= (const int*)d_in[2];
  const float* W1   = (const float*)d_in[3];
  const float* as1  = (const float*)d_in[4];
  const float* ad1  = (const float*)d_in[5];
  const float* b1   = (const float*)d_in[6];
  const float* W2   = (const float*)d_in[7];
  const float* as2  = (const float*)d_in[8];
  const float* ad2  = (const float*)d_in[9];
  const float* b2   = (const float*)d_in[10];
  const float* mw1  = (const float*)d_in[11];
  const float* mb1  = (const float*)d_in[12];
  const float* mw2  = (const float*)d_in[13];
  const float* mb2  = (const float*)d_in[14];
  float* out = (float*)d_out;
  (void)in_sizes; (void)n_in; (void)out_size; (void)ws_size;

  char* wsb = (char*)d_ws;
  size_t off = 0;
  auto alloc = [&](size_t bytes) -> void* {
    void* p = wsb + off;
    off += (bytes + 255) & ~(size_t)255;
    return p;
  };
  u16*  agg    = (u16*)alloc((size_t)MPAD * KDIM * 2);     // 186.4 MB
  u16*  Bt     = (u16*)alloc((size_t)FDIM * KDIM * 2);     // 14.2 MB
  float* h1    = (float*)alloc((size_t)MPAD * FDIM * 4);   // 31.1 MB
  float* h2    = (float*)alloc((size_t)MPAD * FDIM * 4);   // 31.1 MB
  float* sd    = (float*)alloc((size_t)NNODES * 24 * 4);
  float* Ut    = (float*)alloc((size_t)FDIM * 24 * 4);
  u32*  menc   = (u32*)alloc((size_t)NNODES * NHEADS * 4);
  float* den   = (float*)alloc((size_t)NNODES * NHEADS * 4);
  float* ebuf  = (float*)alloc((size_t)ETOT * NHEADS * 4);
  int*  counts = (int*)alloc((size_t)NNODES * 4);
  int*  offs   = (int*)alloc((size_t)(NNODES + 1) * 4);
  int*  cursor = (int*)alloc((size_t)NNODES * 4);
  int*  elist  = (int*)alloc((size_t)ETOT * 4);
  float* gbuf  = (float*)alloc((size_t)NGRAPH * FDIM * 4);

  // CSR by dst (edges identical for both layers)
  hipMemsetAsync(counts, 0, NNODES * 4, stream);
  k_count<<<(ETOT + 255) / 256, 256, 0, stream>>>(ei + NEDGES, counts);
  k_scan<<<1, 256, 0, stream>>>(counts, offs);
  k_seed<<<(NNODES + 255) / 256, 256, 0, stream>>>(offs, cursor);
  k_scatter<<<(ETOT + 255) / 256, 256, 0, stream>>>(ei + NEDGES, cursor, elist);

  for (int layer = 0; layer < 2; layer++) {
    const float* xin  = layer ? h1  : x;
    const float* W    = layer ? W2  : W1;
    const float* asrc = layer ? as2 : as1;
    const float* adst = layer ? ad2 : ad1;
    const float* bb   = layer ? b2  : b1;
    float* hout       = layer ? h2  : h1;

    k_U<<<FDIM, 64, 0, stream>>>(W, asrc, adst, Ut);
    k_sd<<<(NNODES + 3) / 4, 256, 0, stream>>>(xin, Ut, sd);
    k_trans<<<dim3(24, 24, 12), dim3(32, 8), 0, stream>>>(W, Bt);
    hipMemsetAsync(menc, 0, (size_t)NNODES * NHEADS * 4, stream);
    hipMemsetAsync(den, 0, (size_t)NNODES * NHEADS * 4, stream);
    k_edge1<<<(ETOT * NHEADS + 255) / 256, 256, 0, stream>>>(sd, ei, menc, ebuf);
    k_edge2<<<(ETOT * NHEADS + 255) / 256, 256, 0, stream>>>(ebuf, ei, menc, den);
    k_agg<<<NNODES, 256, 0, stream>>>(xin, ei, offs, elist, ebuf, den, agg);
    k_gemm<<<dim3(FDIM / 128, MPAD / 128), 256, 0, stream>>>(agg, Bt, hout, bb, 1.f / 12.f);
  }

  k_pool<<<NGRAPH, 256, 0, stream>>>(h2, batch, gbuf);
  k_mlp<<<NGRAPH, 128, 0, stream>>>(gbuf, mw1, mb1, mw2, mb2, out);
}

// Round 3
// 1156.956 us; speedup vs baseline: 1.5796x; 1.0628x over previous
//
#include <hip/hip_runtime.h>
#include <stdint.h>

typedef unsigned short u16;
typedef unsigned int   u32;

#define NNODES 10000
#define NEDGES 20000
#define ETOT   30000
#define NHEADS 12
#define CDIM   768
#define FDIM   768
#define KDIM   9216
#define NGRAPH 64
#define MPAD   10112   // 79*128
#define SPLITS 4
#define KCH    (KDIM / SPLITS)   // 2304
#define NEG_SLOPE 0.2f

typedef __attribute__((ext_vector_type(8))) short short8;
typedef __attribute__((ext_vector_type(4))) float f32x4;

__device__ __forceinline__ u16 f32_bf16(float f) {
  u32 u = __float_as_uint(f);
  u = (u + 0x7FFFu + ((u >> 16) & 1u)) >> 16;
  return (u16)u;
}
__device__ __forceinline__ u32 enc_f32(float f) {
  u32 u = __float_as_uint(f);
  return (u & 0x80000000u) ? ~u : (u | 0x80000000u);
}
__device__ __forceinline__ float dec_f32(u32 u) {
  u32 v = (u & 0x80000000u) ? (u & 0x7FFFFFFFu) : ~u;
  return __uint_as_float(v);
}

// ---------------- CSR build ----------------
__global__ void k_count(const int* __restrict__ dste, int* __restrict__ counts) {
  int e = blockIdx.x * blockDim.x + threadIdx.x;
  if (e >= ETOT) return;
  int dst;
  if (e < NEDGES) dst = dste[e]; else dst = e - NEDGES;
  atomicAdd(&counts[dst], 1);
}

__global__ void k_scan(const int* __restrict__ counts, int* __restrict__ offs) {
  __shared__ int part[256];
  int t = threadIdx.x;
  const int chunk = 40;  // 256*40 >= 10000
  int beg = t * chunk;
  int end = beg + chunk; if (end > NNODES) end = NNODES;
  int s = 0;
  for (int i = beg; i < end && i < NNODES; i++) s += counts[i];
  part[t] = s;
  __syncthreads();
  for (int d = 1; d < 256; d <<= 1) {
    int v = (t >= d) ? part[t - d] : 0;
    __syncthreads();
    part[t] += v;
    __syncthreads();
  }
  int base = (t == 0) ? 0 : part[t - 1];
  for (int i = beg; i < end && i < NNODES; i++) { offs[i] = base; base += counts[i]; }
  if (t == 255) offs[NNODES] = base;
}

__global__ void k_seed(const int* __restrict__ offs, int* __restrict__ cursor) {
  int n = blockIdx.x * blockDim.x + threadIdx.x;
  if (n < NNODES) cursor[n] = offs[n];
}

__global__ void k_scatter(const int* __restrict__ dste, int* __restrict__ cursor,
                          int* __restrict__ elist) {
  int e = blockIdx.x * blockDim.x + threadIdx.x;
  if (e >= ETOT) return;
  int dst;
  if (e < NEDGES) dst = dste[e]; else dst = e - NEDGES;
  int pos = atomicAdd(&cursor[dst], 1);
  elist[pos] = e;
}

// ------- Ut[o*768+k] = sum_c W[k, h*768+c] * a[h, c]   (o: 0..11 src, 12..23 dst) -------
__global__ void k_U(const float* __restrict__ W, const float* __restrict__ a_src,
                    const float* __restrict__ a_dst, float* __restrict__ Ut) {
  int k = blockIdx.x;
  int l = threadIdx.x;  // 64
  const float* Wrow = W + (size_t)k * KDIM;
  for (int o = 0; o < 24; o++) {
    int h = (o < 12) ? o : o - 12;
    const float* av = (o < 12) ? (a_src + h * CDIM) : (a_dst + h * CDIM);
    const float* wr = Wrow + h * CDIM;
    float p = 0.f;
    for (int c = l; c < CDIM; c += 64) p += wr[c] * av[c];
#pragma unroll
    for (int d = 32; d > 0; d >>= 1) p += __shfl_down(p, d, 64);
    if (l == 0) Ut[o * FDIM + k] = p;
  }
}

// ---- sd[n,0..11]=s, sd[n,12..23]=d : one wave per node, coalesced float4 loads ----
__global__ void k_sd(const float* __restrict__ xin, const float* __restrict__ Ut,
                     float* __restrict__ sd) {
  int t = threadIdx.x, w = t >> 6, l = t & 63;
  int n = blockIdx.x * 4 + w;
  if (n >= NNODES) return;
  const float* xr = xin + (size_t)n * FDIM;
  float4 x0 = *(const float4*)(xr + 4 * l);
  float4 x1 = *(const float4*)(xr + 4 * l + 256);
  float4 x2 = *(const float4*)(xr + 4 * l + 512);
#pragma unroll
  for (int o = 0; o < 24; o++) {
    const float4* up = (const float4*)(Ut + o * FDIM + 4 * l);
    float4 u0 = up[0];
    float4 u1 = up[64];
    float4 u2 = up[128];
    float a = x0.x * u0.x + x0.y * u0.y + x0.z * u0.z + x0.w * u0.w
            + x1.x * u1.x + x1.y * u1.y + x1.z * u1.z + x1.w * u1.w
            + x2.x * u2.x + x2.y * u2.y + x2.z * u2.z + x2.w * u2.w;
#pragma unroll
    for (int d = 32; d > 0; d >>= 1) a += __shfl_xor(a, d, 64);
    if (l == 0) sd[n * 24 + o] = a;
  }
}

// -------- Bt[c, h*768+k] = W[k, h*768+c], bf16 (B^T for the GEMM) --------
__global__ void k_trans(const float* __restrict__ W, u16* __restrict__ Bt) {
  int h = blockIdx.z;
  int kt = blockIdx.x * 32, ct = blockIdx.y * 32;
  int tx = threadIdx.x, ty = threadIdx.y;
  __shared__ float tile[32][33];
#pragma unroll
  for (int r = 0; r < 4; r++)
    tile[ty + 8 * r][tx] = W[(size_t)(kt + ty + 8 * r) * KDIM + h * CDIM + ct + tx];
  __syncthreads();
#pragma unroll
  for (int r = 0; r < 4; r++)
    Bt[(size_t)(ct + ty + 8 * r) * KDIM + h * CDIM + kt + tx] = f32_bf16(tile[tx][ty + 8 * r]);
}

// ---------------- edge logits + segment max ----------------
__global__ void k_edge1(const float* __restrict__ sd, const int* __restrict__ ei,
                        u32* __restrict__ menc, float* __restrict__ ebuf) {
  int tid = blockIdx.x * blockDim.x + threadIdx.x;
  if (tid >= ETOT * NHEADS) return;
  int e = tid / NHEADS, h = tid - e * NHEADS;
  int src, dst;
  if (e < NEDGES) { src = ei[e]; dst = ei[NEDGES + e]; } else { src = e - NEDGES; dst = src; }
  float v = sd[src * 24 + h] + sd[dst * 24 + 12 + h];
  v = (v > 0.f) ? v : NEG_SLOPE * v;
  ebuf[tid] = v;
  atomicMax(&menc[dst * NHEADS + h], enc_f32(v));
}

// ---------------- exp + segment sum ----------------
__global__ void k_edge2(float* __restrict__ ebuf, const int* __restrict__ ei,
                        const u32* __restrict__ menc, float* __restrict__ den) {
  int tid = blockIdx.x * blockDim.x + threadIdx.x;
  if (tid >= ETOT * NHEADS) return;
  int e = tid / NHEADS, h = tid - e * NHEADS;
  int dst;
  if (e < NEDGES) dst = ei[NEDGES + e]; else dst = e - NEDGES;
  float m = dec_f32(menc[dst * NHEADS + h]);
  float ex = expf(ebuf[tid] - m);
  ebuf[tid] = ex;
  atomicAdd(&den[dst * NHEADS + h], ex);
}

// ------- agg[dst, h, k] = sum_e alpha[e,h] * xin[src_e, k]  (bf16 out) -------
__global__ void k_agg(const float* __restrict__ xin, const int* __restrict__ ei,
                      const int* __restrict__ offs, const int* __restrict__ elist,
                      const float* __restrict__ ebuf, const float* __restrict__ den,
                      u16* __restrict__ agg) {
  int n = blockIdx.x;
  int t = threadIdx.x;  // 192
  const float4* dp = (const float4*)(den + (size_t)n * NHEADS);
  float4 dv0 = dp[0], dv1 = dp[1], dv2 = dp[2];
  float iv[NHEADS];
  iv[0] = 1.f / (dv0.x + 1e-16f); iv[1] = 1.f / (dv0.y + 1e-16f);
  iv[2] = 1.f / (dv0.z + 1e-16f); iv[3] = 1.f / (dv0.w + 1e-16f);
  iv[4] = 1.f / (dv1.x + 1e-16f); iv[5] = 1.f / (dv1.y + 1e-16f);
  iv[6] = 1.f / (dv1.z + 1e-16f); iv[7] = 1.f / (dv1.w + 1e-16f);
  iv[8] = 1.f / (dv2.x + 1e-16f); iv[9] = 1.f / (dv2.y + 1e-16f);
  iv[10] = 1.f / (dv2.z + 1e-16f); iv[11] = 1.f / (dv2.w + 1e-16f);
  float4 acc[NHEADS];
#pragma unroll
  for (int h = 0; h < NHEADS; h++) acc[h] = make_float4(0.f, 0.f, 0.f, 0.f);
  int beg = offs[n], end = offs[n + 1];
  for (int idx = beg; idx < end; idx++) {
    int e = elist[idx];
    int src = (e < NEDGES) ? ei[e] : e - NEDGES;
    const float4* ap = (const float4*)(ebuf + (size_t)e * NHEADS);
    float4 a0 = ap[0], a1 = ap[1], a2 = ap[2];
    float al[NHEADS] = {
      a0.x * iv[0], a0.y * iv[1], a0.z * iv[2], a0.w * iv[3],
      a1.x * iv[4], a1.y * iv[5], a1.z * iv[6], a1.w * iv[7],
      a2.x * iv[8], a2.y * iv[9], a2.z * iv[10], a2.w * iv[11]};
    float4 xv = *(const float4*)(xin + (size_t)src * FDIM + 4 * t);
#pragma unroll
    for (int h = 0; h < NHEADS; h++) {
      acc[h].x += al[h] * xv.x; acc[h].y += al[h] * xv.y;
      acc[h].z += al[h] * xv.z; acc[h].w += al[h] * xv.w;
    }
  }
  u16* outr = agg + (size_t)n * KDIM + 4 * t;
#pragma unroll
  for (int h = 0; h < NHEADS; h++) {
    ushort4 pk;
    pk.x = f32_bf16(acc[h].x); pk.y = f32_bf16(acc[h].y);
    pk.z = f32_bf16(acc[h].z); pk.w = f32_bf16(acc[h].w);
    *(ushort4*)(outr + h * CDIM) = pk;
  }
}

// ---- C[MPAD,768] += scale * (A[:,kz] @ Bt[:,kz]^T) (+bias on split 0), split-K atomics ----
__global__ void k_gemm(const u16* __restrict__ A, const u16* __restrict__ B,
                       float* __restrict__ C, const float* __restrict__ bias, float scale) {
  __shared__ __align__(16) u16 As[128 * 32];
  __shared__ __align__(16) u16 Bs[128 * 32];
  int t = threadIdx.x;
  int w = t >> 6, l = t & 63;
  int col0 = blockIdx.x * 128;   // x = col tile (6)
  int row0 = blockIdx.y * 128;   // y = row tile (79)
  int kz = blockIdx.z;           // z = K split (4)
  int kbeg = kz * KCH;
  int wm = (w >> 1) * 64, wn = (w & 1) * 64;
  f32x4 acc[4][4] = {};
  int idx0 = w * 512 + l * 8;      // element index into the 128x32 tile, chunk 0
  int idx1 = idx0 + 2048;          // chunk 1
  const u16* Ag0 = A + (size_t)(row0 + (idx0 >> 5)) * KDIM + (idx0 & 31) + kbeg;
  const u16* Ag1 = A + (size_t)(row0 + (idx1 >> 5)) * KDIM + (idx1 & 31) + kbeg;
  const u16* Bg0 = B + (size_t)(col0 + (idx0 >> 5)) * KDIM + (idx0 & 31) + kbeg;
  const u16* Bg1 = B + (size_t)(col0 + (idx1 >> 5)) * KDIM + (idx1 & 31) + kbeg;
  u16* As0 = As + w * 512;        // wave-uniform LDS bases (lane scatters +l*16B)
  u16* As1 = As + 2048 + w * 512;
  u16* Bs0 = Bs + w * 512;
  u16* Bs1 = Bs + 2048 + w * 512;
  int lr = l & 15, lk = (l >> 4) * 8;

  for (int k0 = 0; k0 < KCH; k0 += 32) {
    __builtin_amdgcn_global_load_lds((__attribute__((address_space(1))) void*)(Ag0 + k0),
                                     (__attribute__((address_space(3))) void*)As0, 16, 0, 0);
    __builtin_amdgcn_global_load_lds((__attribute__((address_space(1))) void*)(Ag1 + k0),
                                     (__attribute__((address_space(3))) void*)As1, 16, 0, 0);
    __builtin_amdgcn_global_load_lds((__attribute__((address_space(1))) void*)(Bg0 + k0),
                                     (__attribute__((address_space(3))) void*)Bs0, 16, 0, 0);
    __builtin_amdgcn_global_load_lds((__attribute__((address_space(1))) void*)(Bg1 + k0),
                                     (__attribute__((address_space(3))) void*)Bs1, 16, 0, 0);
    __syncthreads();
    short8 af[4], bf[4];
#pragma unroll
    for (int i = 0; i < 4; i++) af[i] = *(const short8*)(As + (wm + i * 16 + lr) * 32 + lk);
#pragma unroll
    for (int j = 0; j < 4; j++) bf[j] = *(const short8*)(Bs + (wn + j * 16 + lr) * 32 + lk);
#pragma unroll
    for (int i = 0; i < 4; i++)
#pragma unroll
      for (int j = 0; j < 4; j++)
        acc[i][j] = __builtin_amdgcn_mfma_f32_16x16x32_bf16(af[i], bf[j], acc[i][j], 0, 0, 0);
    __syncthreads();
  }

  int lg = l >> 4;
#pragma unroll
  for (int i = 0; i < 4; i++)
#pragma unroll
    for (int j = 0; j < 4; j++) {
      int col = col0 + wn + j * 16 + lr;
      float badd = (kz == 0) ? bias[col] : 0.f;
#pragma unroll
      for (int r = 0; r < 4; r++) {
        int row = row0 + wm + i * 16 + lg * 4 + r;
        unsafeAtomicAdd(&C[(size_t)row * FDIM + col], acc[i][j][r] * scale + badd);
      }
    }
}

// ---------------- graph mean pool (batch is sorted) ----------------
__global__ void k_pool(const float* __restrict__ h2, const int* __restrict__ batch,
                       float* __restrict__ g) {
  int gi = blockIdx.x;
  int c = blockIdx.y * 256 + threadIdx.x;
  int lo = 0, hi = NNODES;
  while (lo < hi) { int mid = (lo + hi) >> 1; if (batch[mid] < gi) lo = mid + 1; else hi = mid; }
  int start = lo;
  lo = start; hi = NNODES;
  while (lo < hi) { int mid = (lo + hi) >> 1; if (batch[mid] < gi + 1) lo = mid + 1; else hi = mid; }
  int end = lo;
  int cnt = end - start; if (cnt < 1) cnt = 1;
  float inv = 1.f / (float)cnt;
  float s = 0.f;
  for (int n = start; n < end; n++) s += h2[(size_t)n * FDIM + c];
  g[gi * FDIM + c] = s * inv;
}

// ---------------- MLP head ----------------
__global__ void k_mlp(const float* __restrict__ g, const float* __restrict__ w1,
                      const float* __restrict__ b1, const float* __restrict__ w2,
                      const float* __restrict__ b2, float* __restrict__ out) {
  int gi = blockIdx.x;
  int t = threadIdx.x;  // 128
  __shared__ float gs[FDIM];
  __shared__ float zs[128];
  for (int i = t; i < FDIM; i += 128) gs[i] = g[gi * FDIM + i];
  __syncthreads();
  float a = b1[t];
  for (int k = 0; k < FDIM; k++) a += gs[k] * w1[k * 128 + t];
  zs[t] = (a > 0.f) ? a : 0.f;
  __syncthreads();
  if (t < 4) {
    float o = b2[t];
    for (int i = 0; i < 128; i++) o += zs[i] * w2[i * 4 + t];
    out[gi * 4 + t] = o;
  }
}

extern "C" void kernel_launch(void* const* d_in, const int* in_sizes, int n_in,
                              void* d_out, int out_size, void* d_ws, size_t ws_size,
                              hipStream_t stream) {
  const float* x    = (const float*)d_in[0];
  const int*   ei   = (const int*)d_in[1];
  const int*   batch= (const int*)d_in[2];
  const float* W1   = (const float*)d_in[3];
  const float* as1  = (const float*)d_in[4];
  const float* ad1  = (const float*)d_in[5];
  const float* b1   = (const float*)d_in[6];
  const float* W2   = (const float*)d_in[7];
  const float* as2  = (const float*)d_in[8];
  const float* ad2  = (const float*)d_in[9];
  const float* b2   = (const float*)d_in[10];
  const float* mw1  = (const float*)d_in[11];
  const float* mb1  = (const float*)d_in[12];
  const float* mw2  = (const float*)d_in[13];
  const float* mb2  = (const float*)d_in[14];
  float* out = (float*)d_out;
  (void)in_sizes; (void)n_in; (void)out_size; (void)ws_size;

  char* wsb = (char*)d_ws;
  size_t off = 0;
  auto alloc = [&](size_t bytes) -> void* {
    void* p = wsb + off;
    off += (bytes + 255) & ~(size_t)255;
    return p;
  };
  u16*  agg    = (u16*)alloc((size_t)MPAD * KDIM * 2);     // 186.4 MB
  u16*  Bt     = (u16*)alloc((size_t)FDIM * KDIM * 2);     // 14.2 MB
  float* h1    = (float*)alloc((size_t)MPAD * FDIM * 4);   // 31.1 MB
  float* h2    = (float*)alloc((size_t)MPAD * FDIM * 4);   // 31.1 MB
  float* sd    = (float*)alloc((size_t)NNODES * 24 * 4);
  float* Ut    = (float*)alloc((size_t)FDIM * 24 * 4);
  u32*  menc   = (u32*)alloc((size_t)NNODES * NHEADS * 4);
  float* den   = (float*)alloc((size_t)NNODES * NHEADS * 4);
  float* ebuf  = (float*)alloc((size_t)ETOT * NHEADS * 4);
  int*  counts = (int*)alloc((size_t)NNODES * 4);
  int*  offs   = (int*)alloc((size_t)(NNODES + 1) * 4);
  int*  cursor = (int*)alloc((size_t)NNODES * 4);
  int*  elist  = (int*)alloc((size_t)ETOT * 4);
  float* gbuf  = (float*)alloc((size_t)NGRAPH * FDIM * 4);

  // CSR by dst (edges identical for both layers)
  hipMemsetAsync(counts, 0, NNODES * 4, stream);
  k_count<<<(ETOT + 255) / 256, 256, 0, stream>>>(ei + NEDGES, counts);
  k_scan<<<1, 256, 0, stream>>>(counts, offs);
  k_seed<<<(NNODES + 255) / 256, 256, 0, stream>>>(offs, cursor);
  k_scatter<<<(ETOT + 255) / 256, 256, 0, stream>>>(ei + NEDGES, cursor, elist);

  for (int layer = 0; layer < 2; layer++) {
    const float* xin  = layer ? h1  : x;
    const float* W    = layer ? W2  : W1;
    const float* asrc = layer ? as2 : as1;
    const float* adst = layer ? ad2 : ad1;
    const float* bb   = layer ? b2  : b1;
    float* hout       = layer ? h2  : h1;

    k_U<<<FDIM, 64, 0, stream>>>(W, asrc, adst, Ut);
    k_sd<<<(NNODES + 3) / 4, 256, 0, stream>>>(xin, Ut, sd);
    k_trans<<<dim3(24, 24, 12), dim3(32, 8), 0, stream>>>(W, Bt);
    hipMemsetAsync(menc, 0, (size_t)NNODES * NHEADS * 4, stream);
    hipMemsetAsync(den, 0, (size_t)NNODES * NHEADS * 4, stream);
    hipMemsetAsync(hout, 0, (size_t)MPAD * FDIM * 4, stream);
    k_edge1<<<(ETOT * NHEADS + 255) / 256, 256, 0, stream>>>(sd, ei, menc, ebuf);
    k_edge2<<<(ETOT * NHEADS + 255) / 256, 256, 0, stream>>>(ebuf, ei, menc, den);
    k_agg<<<NNODES, 192, 0, stream>>>(xin, ei, offs, elist, ebuf, den, agg);
    k_gemm<<<dim3(FDIM / 128, MPAD / 128, SPLITS), 256, 0, stream>>>(agg, Bt, hout, bb, 1.f / 12.f);
  }

  k_pool<<<dim3(NGRAPH, 3), 256, 0, stream>>>(h2, batch, gbuf);
  k_mlp<<<NGRAPH, 128, 0, stream>>>(gbuf, mw1, mb1, mw2, mb2, out);
}

// Round 4
// 1120.139 us; speedup vs baseline: 1.6315x; 1.0329x over previous
//
#include <hip/hip_runtime.h>
#include <stdint.h>

typedef unsigned short u16;
typedef unsigned int   u32;

#define NNODES 10000
#define NEDGES 20000
#define ETOT   30000
#define NHEADS 12
#define CDIM   768
#define FDIM   768
#define KDIM   9216
#define NGRAPH 64
#define MPAD   10112   // 79*128
#define SPLITS 4
#define KCH    (KDIM / SPLITS)   // 2304
#define NEG_SLOPE 0.2f

typedef __attribute__((ext_vector_type(8))) short short8;
typedef __attribute__((ext_vector_type(4))) float f32x4;

__device__ __forceinline__ u16 f32_bf16(float f) {
  u32 u = __float_as_uint(f);
  u = (u + 0x7FFFu + ((u >> 16) & 1u)) >> 16;
  return (u16)u;
}
__device__ __forceinline__ u32 enc_f32(float f) {
  u32 u = __float_as_uint(f);
  return (u & 0x80000000u) ? ~u : (u | 0x80000000u);
}
__device__ __forceinline__ float dec_f32(u32 u) {
  u32 v = (u & 0x80000000u) ? (u & 0x7FFFFFFFu) : ~u;
  return __uint_as_float(v);
}

// ---------------- CSR build ----------------
__global__ void k_count(const int* __restrict__ dste, int* __restrict__ counts) {
  int e = blockIdx.x * blockDim.x + threadIdx.x;
  if (e >= ETOT) return;
  int dst;
  if (e < NEDGES) dst = dste[e]; else dst = e - NEDGES;
  atomicAdd(&counts[dst], 1);
}

__global__ void k_scan(const int* __restrict__ counts, int* __restrict__ offs) {
  __shared__ int part[256];
  int t = threadIdx.x;
  const int chunk = 40;  // 256*40 >= 10000
  int beg = t * chunk;
  int end = beg + chunk; if (end > NNODES) end = NNODES;
  int s = 0;
  for (int i = beg; i < end && i < NNODES; i++) s += counts[i];
  part[t] = s;
  __syncthreads();
  for (int d = 1; d < 256; d <<= 1) {
    int v = (t >= d) ? part[t - d] : 0;
    __syncthreads();
    part[t] += v;
    __syncthreads();
  }
  int base = (t == 0) ? 0 : part[t - 1];
  for (int i = beg; i < end && i < NNODES; i++) { offs[i] = base; base += counts[i]; }
  if (t == 255) offs[NNODES] = base;
}

__global__ void k_seed(const int* __restrict__ offs, int* __restrict__ cursor) {
  int n = blockIdx.x * blockDim.x + threadIdx.x;
  if (n < NNODES) cursor[n] = offs[n];
}

__global__ void k_scatter(const int* __restrict__ dste, int* __restrict__ cursor,
                          int* __restrict__ elist) {
  int e = blockIdx.x * blockDim.x + threadIdx.x;
  if (e >= ETOT) return;
  int dst;
  if (e < NEDGES) dst = dste[e]; else dst = e - NEDGES;
  int pos = atomicAdd(&cursor[dst], 1);
  elist[pos] = e;
}

// ------- Ut[o*768+k] = sum_c W[k, h*768+c] * a[h, c]   (o: 0..11 src, 12..23 dst) -------
__global__ void k_U(const float* __restrict__ W, const float* __restrict__ a_src,
                    const float* __restrict__ a_dst, float* __restrict__ Ut) {
  int k = blockIdx.x;
  int l = threadIdx.x;  // 64
  const float* Wrow = W + (size_t)k * KDIM;
  for (int o = 0; o < 24; o++) {
    int h = (o < 12) ? o : o - 12;
    const float* av = (o < 12) ? (a_src + h * CDIM) : (a_dst + h * CDIM);
    const float* wr = Wrow + h * CDIM;
    float p = 0.f;
    for (int c = l; c < CDIM; c += 64) p += wr[c] * av[c];
#pragma unroll
    for (int d = 32; d > 0; d >>= 1) p += __shfl_down(p, d, 64);
    if (l == 0) Ut[o * FDIM + k] = p;
  }
}

// ---- sd[n,0..11]=s, sd[n,12..23]=d : one wave per node, coalesced float4 loads ----
__global__ void k_sd(const float* __restrict__ xin, const float* __restrict__ Ut,
                     float* __restrict__ sd) {
  int t = threadIdx.x, w = t >> 6, l = t & 63;
  int n = blockIdx.x * 4 + w;
  if (n >= NNODES) return;
  const float* xr = xin + (size_t)n * FDIM;
  float4 x0 = *(const float4*)(xr + 4 * l);
  float4 x1 = *(const float4*)(xr + 4 * l + 256);
  float4 x2 = *(const float4*)(xr + 4 * l + 512);
#pragma unroll
  for (int o = 0; o < 24; o++) {
    const float4* up = (const float4*)(Ut + o * FDIM + 4 * l);
    float4 u0 = up[0];
    float4 u1 = up[64];
    float4 u2 = up[128];
    float a = x0.x * u0.x + x0.y * u0.y + x0.z * u0.z + x0.w * u0.w
            + x1.x * u1.x + x1.y * u1.y + x1.z * u1.z + x1.w * u1.w
            + x2.x * u2.x + x2.y * u2.y + x2.z * u2.z + x2.w * u2.w;
#pragma unroll
    for (int d = 32; d > 0; d >>= 1) a += __shfl_xor(a, d, 64);
    if (l == 0) sd[n * 24 + o] = a;
  }
}

// -------- Bt[c, h*768+k] = W[k, h*768+c], bf16 (B^T for the GEMM) --------
__global__ void k_trans(const float* __restrict__ W, u16* __restrict__ Bt) {
  int h = blockIdx.z;
  int kt = blockIdx.x * 32, ct = blockIdx.y * 32;
  int tx = threadIdx.x, ty = threadIdx.y;
  __shared__ float tile[32][33];
#pragma unroll
  for (int r = 0; r < 4; r++)
    tile[ty + 8 * r][tx] = W[(size_t)(kt + ty + 8 * r) * KDIM + h * CDIM + ct + tx];
  __syncthreads();
#pragma unroll
  for (int r = 0; r < 4; r++)
    Bt[(size_t)(ct + ty + 8 * r) * KDIM + h * CDIM + kt + tx] = f32_bf16(tile[tx][ty + 8 * r]);
}

// ---------------- edge logits + segment max ----------------
__global__ void k_edge1(const float* __restrict__ sd, const int* __restrict__ ei,
                        u32* __restrict__ menc, float* __restrict__ ebuf) {
  int tid = blockIdx.x * blockDim.x + threadIdx.x;
  if (tid >= ETOT * NHEADS) return;
  int e = tid / NHEADS, h = tid - e * NHEADS;
  int src, dst;
  if (e < NEDGES) { src = ei[e]; dst = ei[NEDGES + e]; } else { src = e - NEDGES; dst = src; }
  float v = sd[src * 24 + h] + sd[dst * 24 + 12 + h];
  v = (v > 0.f) ? v : NEG_SLOPE * v;
  ebuf[tid] = v;
  atomicMax(&menc[dst * NHEADS + h], enc_f32(v));
}

// ---------------- exp + segment sum ----------------
__global__ void k_edge2(float* __restrict__ ebuf, const int* __restrict__ ei,
                        const u32* __restrict__ menc, float* __restrict__ den) {
  int tid = blockIdx.x * blockDim.x + threadIdx.x;
  if (tid >= ETOT * NHEADS) return;
  int e = tid / NHEADS, h = tid - e * NHEADS;
  int dst;
  if (e < NEDGES) dst = ei[NEDGES + e]; else dst = e - NEDGES;
  float m = dec_f32(menc[dst * NHEADS + h]);
  float ex = expf(ebuf[tid] - m);
  ebuf[tid] = ex;
  atomicAdd(&den[dst * NHEADS + h], ex);
}

// ------- agg[dst, h, k] = sum_e alpha[e,h] * xin[src_e, k]  (bf16 out) -------
__global__ void k_agg(const float* __restrict__ xin, const int* __restrict__ ei,
                      const int* __restrict__ offs, const int* __restrict__ elist,
                      const float* __restrict__ ebuf, const float* __restrict__ den,
                      u16* __restrict__ agg) {
  int n = blockIdx.x;
  int t = threadIdx.x;  // 192
  const float4* dp = (const float4*)(den + (size_t)n * NHEADS);
  float4 dv0 = dp[0], dv1 = dp[1], dv2 = dp[2];
  float iv[NHEADS];
  iv[0] = 1.f / (dv0.x + 1e-16f); iv[1] = 1.f / (dv0.y + 1e-16f);
  iv[2] = 1.f / (dv0.z + 1e-16f); iv[3] = 1.f / (dv0.w + 1e-16f);
  iv[4] = 1.f / (dv1.x + 1e-16f); iv[5] = 1.f / (dv1.y + 1e-16f);
  iv[6] = 1.f / (dv1.z + 1e-16f); iv[7] = 1.f / (dv1.w + 1e-16f);
  iv[8] = 1.f / (dv2.x + 1e-16f); iv[9] = 1.f / (dv2.y + 1e-16f);
  iv[10] = 1.f / (dv2.z + 1e-16f); iv[11] = 1.f / (dv2.w + 1e-16f);
  float4 acc[NHEADS];
#pragma unroll
  for (int h = 0; h < NHEADS; h++) acc[h] = make_float4(0.f, 0.f, 0.f, 0.f);
  int beg = offs[n], end = offs[n + 1];
  for (int idx = beg; idx < end; idx++) {
    int e = elist[idx];
    int src = (e < NEDGES) ? ei[e] : e - NEDGES;
    const float4* ap = (const float4*)(ebuf + (size_t)e * NHEADS);
    float4 a0 = ap[0], a1 = ap[1], a2 = ap[2];
    float al[NHEADS] = {
      a0.x * iv[0], a0.y * iv[1], a0.z * iv[2], a0.w * iv[3],
      a1.x * iv[4], a1.y * iv[5], a1.z * iv[6], a1.w * iv[7],
      a2.x * iv[8], a2.y * iv[9], a2.z * iv[10], a2.w * iv[11]};
    float4 xv = *(const float4*)(xin + (size_t)src * FDIM + 4 * t);
#pragma unroll
    for (int h = 0; h < NHEADS; h++) {
      acc[h].x += al[h] * xv.x; acc[h].y += al[h] * xv.y;
      acc[h].z += al[h] * xv.z; acc[h].w += al[h] * xv.w;
    }
  }
  u16* outr = agg + (size_t)n * KDIM + 4 * t;
#pragma unroll
  for (int h = 0; h < NHEADS; h++) {
    ushort4 pk;
    pk.x = f32_bf16(acc[h].x); pk.y = f32_bf16(acc[h].y);
    pk.z = f32_bf16(acc[h].z); pk.w = f32_bf16(acc[h].w);
    *(ushort4*)(outr + h * CDIM) = pk;
  }
}

// ---- C[MPAD,768] += scale * (A[:,kz] @ Bt[:,kz]^T), split-K atomics, dbuf LDS,
//      XCD-swizzled 1D grid: xcd=lin&7 owns (z=xcd>>1, cols (xcd&1)*3..+2), streams y ----
__global__ void k_gemm(const u16* __restrict__ A, const u16* __restrict__ B,
                       float* __restrict__ C, const float* __restrict__ bias, float scale) {
  __shared__ __align__(16) u16 As[2][128 * 32];
  __shared__ __align__(16) u16 Bs[2][128 * 32];
  int t = threadIdx.x;
  int w = t >> 6, l = t & 63;
  // swizzle decode: lin = 0..1895 ; 1896 = 8 * 237, 237 = 3 * 79
  int lin = blockIdx.x;
  int xcd = lin & 7;
  int s = lin >> 3;              // 0..236
  int kz = xcd >> 1;             // 0..3  (K split pinned per XCD pair)
  int colt = (xcd & 1) * 3 + (s % 3);  // 0..5
  int y = s / 3;                 // 0..78
  int col0 = colt * 128;
  int row0 = y * 128;
  int kbeg = kz * KCH;
  int wm = (w >> 1) * 64, wn = (w & 1) * 64;
  f32x4 acc[4][4] = {};
  int idx0 = w * 512 + l * 8;      // element index into the 128x32 tile, chunk 0
  int idx1 = idx0 + 2048;          // chunk 1
  const u16* Ag0 = A + (size_t)(row0 + (idx0 >> 5)) * KDIM + (idx0 & 31) + kbeg;
  const u16* Ag1 = A + (size_t)(row0 + (idx1 >> 5)) * KDIM + (idx1 & 31) + kbeg;
  const u16* Bg0 = B + (size_t)(col0 + (idx0 >> 5)) * KDIM + (idx0 & 31) + kbeg;
  const u16* Bg1 = B + (size_t)(col0 + (idx1 >> 5)) * KDIM + (idx1 & 31) + kbeg;
  int wo = w * 512;
  int lr = l & 15, lk = (l >> 4) * 8;

  auto issue = [&](int buf, int k0) {
    __builtin_amdgcn_global_load_lds((__attribute__((address_space(1))) void*)(Ag0 + k0),
                                     (__attribute__((address_space(3))) void*)(&As[buf][wo]), 16, 0, 0);
    __builtin_amdgcn_global_load_lds((__attribute__((address_space(1))) void*)(Ag1 + k0),
                                     (__attribute__((address_space(3))) void*)(&As[buf][2048 + wo]), 16, 0, 0);
    __builtin_amdgcn_global_load_lds((__attribute__((address_space(1))) void*)(Bg0 + k0),
                                     (__attribute__((address_space(3))) void*)(&Bs[buf][wo]), 16, 0, 0);
    __builtin_amdgcn_global_load_lds((__attribute__((address_space(1))) void*)(Bg1 + k0),
                                     (__attribute__((address_space(3))) void*)(&Bs[buf][2048 + wo]), 16, 0, 0);
  };

  issue(0, 0);
  __syncthreads();              // buf0 ready
  const int NIT = KCH / 32;     // 72
  int cur = 0;
  for (int it = 0; it < NIT; it++) {
    if (it + 1 < NIT) issue(cur ^ 1, (it + 1) * 32);   // prefetch next tile into other buffer
    short8 af[4], bf[4];
#pragma unroll
    for (int i = 0; i < 4; i++) af[i] = *(const short8*)(&As[cur][(wm + i * 16 + lr) * 32 + lk]);
#pragma unroll
    for (int j = 0; j < 4; j++) bf[j] = *(const short8*)(&Bs[cur][(wn + j * 16 + lr) * 32 + lk]);
#pragma unroll
    for (int i = 0; i < 4; i++)
#pragma unroll
      for (int j = 0; j < 4; j++)
        acc[i][j] = __builtin_amdgcn_mfma_f32_16x16x32_bf16(af[i], bf[j], acc[i][j], 0, 0, 0);
    __syncthreads();            // (a) all waves done reading cur  (b) drains prefetch vmcnt
    cur ^= 1;
  }

  int lg = l >> 4;
#pragma unroll
  for (int i = 0; i < 4; i++)
#pragma unroll
    for (int j = 0; j < 4; j++) {
      int col = col0 + wn + j * 16 + lr;
      float badd = (kz == 0) ? bias[col] : 0.f;
#pragma unroll
      for (int r = 0; r < 4; r++) {
        int row = row0 + wm + i * 16 + lg * 4 + r;
        unsafeAtomicAdd(&C[(size_t)row * FDIM + col], acc[i][j][r] * scale + badd);
      }
    }
}

// ---------------- graph mean pool (batch is sorted) ----------------
__global__ void k_pool(const float* __restrict__ h2, const int* __restrict__ batch,
                       float* __restrict__ g) {
  int gi = blockIdx.x;
  int c = blockIdx.y * 256 + threadIdx.x;
  int lo = 0, hi = NNODES;
  while (lo < hi) { int mid = (lo + hi) >> 1; if (batch[mid] < gi) lo = mid + 1; else hi = mid; }
  int start = lo;
  lo = start; hi = NNODES;
  while (lo < hi) { int mid = (lo + hi) >> 1; if (batch[mid] < gi + 1) lo = mid + 1; else hi = mid; }
  int end = lo;
  int cnt = end - start; if (cnt < 1) cnt = 1;
  float inv = 1.f / (float)cnt;
  float s = 0.f;
  for (int n = start; n < end; n++) s += h2[(size_t)n * FDIM + c];
  g[gi * FDIM + c] = s * inv;
}

// ---------------- MLP head ----------------
__global__ void k_mlp(const float* __restrict__ g, const float* __restrict__ w1,
                      const float* __restrict__ b1, const float* __restrict__ w2,
                      const float* __restrict__ b2, float* __restrict__ out) {
  int gi = blockIdx.x;
  int t = threadIdx.x;  // 128
  __shared__ float gs[FDIM];
  __shared__ float zs[128];
  for (int i = t; i < FDIM; i += 128) gs[i] = g[gi * FDIM + i];
  __syncthreads();
  float a = b1[t];
  for (int k = 0; k < FDIM; k++) a += gs[k] * w1[k * 128 + t];
  zs[t] = (a > 0.f) ? a : 0.f;
  __syncthreads();
  if (t < 4) {
    float o = b2[t];
    for (int i = 0; i < 128; i++) o += zs[i] * w2[i * 4 + t];
    out[gi * 4 + t] = o;
  }
}

extern "C" void kernel_launch(void* const* d_in, const int* in_sizes, int n_in,
                              void* d_out, int out_size, void* d_ws, size_t ws_size,
                              hipStream_t stream) {
  const float* x    = (const float*)d_in[0];
  const int*   ei   = (const int*)d_in[1];
  const int*   batch= (const int*)d_in[2];
  const float* W1   = (const float*)d_in[3];
  const float* as1  = (const float*)d_in[4];
  const float* ad1  = (const float*)d_in[5];
  const float* b1   = (const float*)d_in[6];
  const float* W2   = (const float*)d_in[7];
  const float* as2  = (const float*)d_in[8];
  const float* ad2  = (const float*)d_in[9];
  const float* b2   = (const float*)d_in[10];
  const float* mw1  = (const float*)d_in[11];
  const float* mb1  = (const float*)d_in[12];
  const float* mw2  = (const float*)d_in[13];
  const float* mb2  = (const float*)d_in[14];
  float* out = (float*)d_out;
  (void)in_sizes; (void)n_in; (void)out_size; (void)ws_size;

  char* wsb = (char*)d_ws;
  size_t off = 0;
  auto alloc = [&](size_t bytes) -> void* {
    void* p = wsb + off;
    off += (bytes + 255) & ~(size_t)255;
    return p;
  };
  u16*  agg    = (u16*)alloc((size_t)MPAD * KDIM * 2);     // 186.4 MB
  u16*  Bt     = (u16*)alloc((size_t)FDIM * KDIM * 2);     // 14.2 MB
  float* h1    = (float*)alloc((size_t)MPAD * FDIM * 4);   // 31.1 MB
  float* h2    = (float*)alloc((size_t)MPAD * FDIM * 4);   // 31.1 MB
  float* sd    = (float*)alloc((size_t)NNODES * 24 * 4);
  float* Ut    = (float*)alloc((size_t)FDIM * 24 * 4);
  u32*  menc   = (u32*)alloc((size_t)NNODES * NHEADS * 4);
  float* den   = (float*)alloc((size_t)NNODES * NHEADS * 4);
  float* ebuf  = (float*)alloc((size_t)ETOT * NHEADS * 4);
  int*  counts = (int*)alloc((size_t)NNODES * 4);
  int*  offs   = (int*)alloc((size_t)(NNODES + 1) * 4);
  int*  cursor = (int*)alloc((size_t)NNODES * 4);
  int*  elist  = (int*)alloc((size_t)ETOT * 4);
  float* gbuf  = (float*)alloc((size_t)NGRAPH * FDIM * 4);

  // CSR by dst (edges identical for both layers)
  hipMemsetAsync(counts, 0, NNODES * 4, stream);
  k_count<<<(ETOT + 255) / 256, 256, 0, stream>>>(ei + NEDGES, counts);
  k_scan<<<1, 256, 0, stream>>>(counts, offs);
  k_seed<<<(NNODES + 255) / 256, 256, 0, stream>>>(offs, cursor);
  k_scatter<<<(ETOT + 255) / 256, 256, 0, stream>>>(ei + NEDGES, cursor, elist);

  for (int layer = 0; layer < 2; layer++) {
    const float* xin  = layer ? h1  : x;
    const float* W    = layer ? W2  : W1;
    const float* asrc = layer ? as2 : as1;
    const float* adst = layer ? ad2 : ad1;
    const float* bb   = layer ? b2  : b1;
    float* hout       = layer ? h2  : h1;

    k_U<<<FDIM, 64, 0, stream>>>(W, asrc, adst, Ut);
    k_sd<<<(NNODES + 3) / 4, 256, 0, stream>>>(xin, Ut, sd);
    k_trans<<<dim3(24, 24, 12), dim3(32, 8), 0, stream>>>(W, Bt);
    hipMemsetAsync(menc, 0, (size_t)NNODES * NHEADS * 4, stream);
    hipMemsetAsync(den, 0, (size_t)NNODES * NHEADS * 4, stream);
    hipMemsetAsync(hout, 0, (size_t)MPAD * FDIM * 4, stream);
    k_edge1<<<(ETOT * NHEADS + 255) / 256, 256, 0, stream>>>(sd, ei, menc, ebuf);
    k_edge2<<<(ETOT * NHEADS + 255) / 256, 256, 0, stream>>>(ebuf, ei, menc, den);
    k_agg<<<NNODES, 192, 0, stream>>>(xin, ei, offs, elist, ebuf, den, agg);
    k_gemm<<<8 * 237, 256, 0, stream>>>(agg, Bt, hout, bb, 1.f / 12.f);
  }

  k_pool<<<dim3(NGRAPH, 3), 256, 0, stream>>>(h2, batch, gbuf);
  k_mlp<<<NGRAPH, 128, 0, stream>>>(gbuf, mw1, mb1, mw2, mb2, out);
}